// Round 8
// baseline (1923.000 us; speedup 1.0000x reference)
//
#include <hip/hip_runtime.h>
#include <hip/hip_bf16.h>
#include <math.h>

// Problem constants (fixed by the reference)
#define TT 4096   // tokens = B*S
#define PP 8192   // pairs  = TT*K
#define DD 1024   // model dim
#define HH 2048   // expert hidden
#define EE 8      // experts
#define CC1 4096  // 2H (up-proj width)

typedef __attribute__((ext_vector_type(8))) short s16x8;
typedef __attribute__((ext_vector_type(4))) float f32x4;

// ---------------- workspace layout (bytes) ----------------
#define W1T_OFF   0ull                                   // bf16 [E][4096][1024]  64 MB
#define W2T_OFF   (W1T_OFF + (size_t)EE*DD*CC1*2)        // bf16 [E][1024][2048]  32 MB
#define XB_OFF    (W2T_OFF + (size_t)EE*HH*DD*2)         // bf16 [T][1024]         8 MB
#define ABUF_OFF  (XB_OFF  + (size_t)TT*DD*2)            // bf16 [P][2048]        32 MB
#define DOWN_OFF  (ABUF_OFF + (size_t)PP*HH*2)           // bf16 [2][P][1024]     32 MB
#define META_OFF  (DOWN_OFF + (size_t)2*PP*DD*2)         // int meta[512] (2 KB)
#define PAIR_OFF  (META_OFF + 2048)                      // int [P]
#define POS_OFF   (PAIR_OFF + (size_t)PP*4)              // int [P]

#define VMCNT(N) asm volatile("s_waitcnt vmcnt(" #N ")" ::: "memory")
#define CFENCE() asm volatile("" ::: "memory")

__device__ __forceinline__ unsigned short f2bf(float f) {
  union { float f; unsigned u; } a; a.f = f;
  unsigned u = a.u;
  unsigned r = u + 0x7FFFu + ((u >> 16) & 1u);   // round-to-nearest-even
  return (unsigned short)(r >> 16);
}

__device__ __forceinline__ float bf2f(unsigned short s) {
  union { unsigned u; float f; } a; a.u = ((unsigned)s) << 16;
  return a.f;
}

// async global->LDS, 16B per lane; LDS dest must be wave-uniform base + lane*16
__device__ __forceinline__ void gload16(const void* g, void* l) {
  __builtin_amdgcn_global_load_lds(
      (const __attribute__((address_space(1))) void*)(uintptr_t)g,
      (__attribute__((address_space(3))) void*)(unsigned)(uintptr_t)l,
      16, 0, 0);
}

// ---------------- x -> bf16 ----------------
__global__ void k_cvt_x(const float* __restrict__ in, unsigned short* __restrict__ out, int n4) {
  int i = blockIdx.x * blockDim.x + threadIdx.x;
  if (i >= n4) return;
  float4 v = reinterpret_cast<const float4*>(in)[i];
  ushort4 o;
  o.x = f2bf(v.x); o.y = f2bf(v.y); o.z = f2bf(v.z); o.w = f2bf(v.w);
  reinterpret_cast<ushort4*>(out)[i] = o;
}

// ---------------- W [R][C] f32 -> Wt [C][R] bf16 (per matrix in grid.z) ----------------
__global__ __launch_bounds__(256) void k_transpose(const float* __restrict__ in,
                                                   unsigned short* __restrict__ out,
                                                   int R, int C) {
  __shared__ float t[64][65];
  const size_t mbase = (size_t)blockIdx.z * (size_t)R * (size_t)C;
  int c0 = blockIdx.x * 64, r0 = blockIdx.y * 64;
  int tid = threadIdx.x;
#pragma unroll
  for (int i = 0; i < 4; ++i) {
    int ch = tid + i * 256;            // 1024 chunks of float4
    int row = ch >> 4, c4 = (ch & 15) * 4;
    float4 v = *reinterpret_cast<const float4*>(&in[mbase + (size_t)(r0 + row) * C + c0 + c4]);
    t[row][c4] = v.x; t[row][c4 + 1] = v.y; t[row][c4 + 2] = v.z; t[row][c4 + 3] = v.w;
  }
  __syncthreads();
#pragma unroll
  for (int i = 0; i < 4; ++i) {
    int ch = tid + i * 256;
    int c = ch >> 4, rb = (ch & 15) * 4;
    ushort4 o;
    o.x = f2bf(t[rb][c]); o.y = f2bf(t[rb + 1][c]);
    o.z = f2bf(t[rb + 2][c]); o.w = f2bf(t[rb + 3][c]);
    *reinterpret_cast<ushort4*>(&out[mbase + (size_t)(c0 + c) * R + r0 + rb]) = o;
  }
}

// ---------------- routing: bucket pairs by expert, 256-row tile list, inverse perm ----------
// meta[0]=ntiles256; meta[1..9]=offsets[0..8]; meta[16+2i]/(17+2i) = (expert,q0)
__global__ void k_route(const int* __restrict__ eidx, int* __restrict__ meta,
                        int* __restrict__ plist, int* __restrict__ pos) {
  __shared__ int cnt[EE], off[EE + 1], cur[EE];
  int tid = threadIdx.x;
  if (tid < EE) { cnt[tid] = 0; cur[tid] = 0; }
  __syncthreads();
  for (int p = tid; p < PP; p += blockDim.x) atomicAdd(&cnt[eidx[p]], 1);
  __syncthreads();
  if (tid == 0) {
    int s = 0;
    for (int e = 0; e < EE; ++e) { off[e] = s; s += cnt[e]; }
    off[EE] = s;
    int n256 = 0;
    for (int e = 0; e < EE; ++e)
      for (int r = 0; r < cnt[e]; r += 256) {
        meta[16 + 2*n256] = e; meta[17 + 2*n256] = off[e] + r; ++n256;
      }
    meta[0] = n256;
    for (int e = 0; e <= EE; ++e) meta[1 + e] = off[e];
  }
  __syncthreads();
  for (int p = tid; p < PP; p += blockDim.x) {
    int e = eidx[p];
    int q = off[e] + atomicAdd(&cur[e], 1);
    plist[q] = p;
    pos[p] = q;
  }
}

// ---------------- GEMM1: up = x @ W1[e], fused GLU + gate, bf16 out (sorted order) ----------
// A direct per-lane global->reg (double-buffered), B-only LDS (3 x 16 KB, depth-2,
// counted vmcnt + raw s_barrier, XOR swizzle both-sides). 256x128 tile, 8 waves 4Mx2N,
// 3 blocks/CU. grid: (40 row-tiles, 32 col-tiles); block 512
__global__ __launch_bounds__(512, 6) void k_gemm1(
    const unsigned short* __restrict__ xb,     // [T][1024] bf16
    const unsigned short* __restrict__ w1t,    // [E][4096][1024] bf16 ([col][k])
    const float* __restrict__ gates,           // [P] f32
    const int* __restrict__ meta,
    const int* __restrict__ plist,
    unsigned short* __restrict__ abuf)         // [P][2048] bf16
{
  const int nt = meta[0];
  const int tb = blockIdx.x;
  if (tb >= nt) return;
  const int e  = meta[16 + 2*tb];
  const int q0 = meta[17 + 2*tb];
  const int nrows = min(256, meta[2 + e] - q0);
  const int c0 = blockIdx.y * 64;              // h-col base

  __shared__ unsigned short Bs[3][128 * 64];   // 48 KB total

  const int tid = threadIdx.x;                 // 0..511
  const int wave = tid >> 6, lane = tid & 63;
  const int l15 = lane & 15, l4 = lane >> 4;
  const int wr = wave >> 1, wc = wave & 1;     // 4M x 2N wave grid

  const unsigned short* w1e = w1t + (size_t)e * CC1 * DD;

  // per-lane A row pointers (pre-offset by l4*8 k-elements)
  const unsigned short* arow[4];
#pragma unroll
  for (int rf = 0; rf < 4; ++rf) {
    int row = wr * 64 + rf * 16 + l15;
    int r = row < nrows ? row : 0;
    int p = plist[q0 + r];
    arow[rf] = xb + (size_t)(p >> 1) * DD + l4 * 8;
  }

  // B staging sources (2 x 16B per thread per K-step), pre-swizzled k-slot
  const unsigned short* bga[2];
#pragma unroll
  for (int i = 0; i < 2; ++i) {
    int c = tid + i * 512;                     // 0..1023
    int row = c >> 3;                          // 0..127
    int ko = ((c & 7) ^ (row & 7)) * 8;
    int u = row & 63, wcq = row >> 6;
    int col = (u < 32) ? (c0 + wcq * 32 + u) : (HH + c0 + wcq * 32 + (u - 32));
    bga[i] = w1e + (size_t)col * DD + ko;
  }

  f32x4 acc[4][4];
#pragma unroll
  for (int a = 0; a < 4; ++a)
#pragma unroll
    for (int b = 0; b < 4; ++b) acc[a][b] = (f32x4)0.0f;

  s16x8 afA[2][4], afB[2][4];

  auto stageB = [&](int kk, unsigned short* pb) {
#pragma unroll
    for (int i = 0; i < 2; ++i) gload16(bga[i] + kk, pb + (tid + i * 512) * 8);
  };
  auto loadA = [&](int kk, s16x8 (*af)[4]) {
#pragma unroll
    for (int ks = 0; ks < 2; ++ks)
#pragma unroll
      for (int rf = 0; rf < 4; ++rf)
        af[ks][rf] = *reinterpret_cast<const s16x8*>(arow[rf] + kk + ks * 32);
  };
  auto compute = [&](s16x8 (*af)[4], const unsigned short* sb) {
    const char* B8 = (const char*)sb;
#pragma unroll
    for (int ks = 0; ks < 2; ++ks) {
      s16x8 bfr[4];
#pragma unroll
      for (int cf = 0; cf < 4; ++cf) {
        int row = wc * 64 + cf * 16 + l15;
        bfr[cf] = *(const s16x8*)(B8 + ((row * 128 + ks * 64 + l4 * 16) ^ ((row & 7) << 4)));
      }
#pragma unroll
      for (int rf = 0; rf < 4; ++rf)
#pragma unroll
        for (int cf = 0; cf < 4; ++cf)
          acc[rf][cf] = __builtin_amdgcn_mfma_f32_16x16x32_bf16(af[ks][rf], bfr[cf], acc[rf][cf], 0, 0, 0);
    }
  };

  unsigned short *p0 = Bs[0], *p1 = Bs[1], *p2 = Bs[2];

  // prologue: B(0), B(1) staged; A(0) loaded
  stageB(0, p0);
  stageB(64, p1);
  loadA(0, afA);
  VMCNT(0);
  __builtin_amdgcn_s_barrier();
  CFENCE();

  // pairs (kp, kp+1), kp = 0,2,...,12 ; K-steps 0..13 computed here
  for (int kp = 0; kp < 14; kp += 2) {
    loadA((kp + 1) * 64, afB);
    stageB((kp + 2) * 64, p2);
    compute(afA, p0);
    VMCNT(2);                                  // afB landed; B(kp+2) may fly
    __builtin_amdgcn_s_barrier();
    CFENCE();
    loadA((kp + 2) * 64, afA);
    stageB((kp + 3) * 64, p0);                 // overwrites buf read at kp (post-barrier)
    compute(afB, p1);
    VMCNT(2);                                  // afA landed; B(kp+3) may fly
    __builtin_amdgcn_s_barrier();
    CFENCE();
    unsigned short* t = p0; p0 = p2; p2 = p1; p1 = t;  // advance by 2
  }
  // peeled K-steps 14, 15
  loadA(15 * 64, afB);
  compute(afA, p0);
  VMCNT(0);
  __builtin_amdgcn_s_barrier();
  CFENCE();
  compute(afB, p1);

  // Epilogue: a = gelu_exact(h) * (g+1) * gate, bf16.
  // acc[rf][cf]: cf 0,1 = h cols, cf 2,3 = matching g cols (same wave).
#pragma unroll
  for (int rf = 0; rf < 4; ++rf) {
#pragma unroll
    for (int i = 0; i < 4; ++i) {
      int r = wr * 64 + rf * 16 + l4 * 4 + i;
      if (r < nrows) {
        int q = q0 + r;
        float gt = gates[plist[q]];
        unsigned short* orow = abuf + (size_t)q * HH + c0 + wc * 32 + l15;
#pragma unroll
        for (int cf = 0; cf < 2; ++cf) {
          float hv = acc[rf][cf][i];
          float gv = acc[rf][cf + 2][i];
          float av = 0.5f * hv * (1.0f + erff(hv * 0.70710678118654752f)) * (gv + 1.0f) * gt;
          orow[cf * 16] = f2bf(av);
        }
      }
    }
  }
}

// ---------------- GEMM2: down_z = a @ W2[e][kz:], bf16 partials (K-split 2) --------------
// Same direct-A / B-only-LDS template; grid: (40 row-tiles, 8 col-tiles, 2 K-halves); 512 thr
__global__ __launch_bounds__(512, 6) void k_gemm2(
    const unsigned short* __restrict__ abuf,   // [P][2048] bf16
    const unsigned short* __restrict__ w2t,    // [E][1024][2048] bf16 ([col][k])
    const int* __restrict__ meta,
    unsigned short* __restrict__ down)         // [2][P][1024] bf16
{
  const int nt = meta[0];
  const int tb = blockIdx.x;
  if (tb >= nt) return;
  const int e  = meta[16 + 2*tb];
  const int q0 = meta[17 + 2*tb];
  const int nrows = min(256, meta[2 + e] - q0);
  const int c0 = blockIdx.y * 128;
  const int kz = blockIdx.z * (HH / 2);

  __shared__ unsigned short Bs[3][128 * 64];   // 48 KB

  const int tid = threadIdx.x;
  const int wave = tid >> 6, lane = tid & 63;
  const int l15 = lane & 15, l4 = lane >> 4;
  const int wr = wave >> 1, wc = wave & 1;

  const unsigned short* w2e = w2t + (size_t)e * DD * HH;

  const unsigned short* arow[4];
#pragma unroll
  for (int rf = 0; rf < 4; ++rf) {
    int row = wr * 64 + rf * 16 + l15;
    int r = row < nrows ? row : 0;
    arow[rf] = abuf + (size_t)(q0 + r) * HH + kz + l4 * 8;
  }

  const unsigned short* bga[2];
#pragma unroll
  for (int i = 0; i < 2; ++i) {
    int c = tid + i * 512;
    int row = c >> 3;                          // 0..127
    int ko = ((c & 7) ^ (row & 7)) * 8;
    bga[i] = w2e + (size_t)(c0 + row) * HH + kz + ko;
  }

  f32x4 acc[4][4];
#pragma unroll
  for (int a = 0; a < 4; ++a)
#pragma unroll
    for (int b = 0; b < 4; ++b) acc[a][b] = (f32x4)0.0f;

  s16x8 afA[2][4], afB[2][4];

  auto stageB = [&](int kk, unsigned short* pb) {
#pragma unroll
    for (int i = 0; i < 2; ++i) gload16(bga[i] + kk, pb + (tid + i * 512) * 8);
  };
  auto loadA = [&](int kk, s16x8 (*af)[4]) {
#pragma unroll
    for (int ks = 0; ks < 2; ++ks)
#pragma unroll
      for (int rf = 0; rf < 4; ++rf)
        af[ks][rf] = *reinterpret_cast<const s16x8*>(arow[rf] + kk + ks * 32);
  };
  auto compute = [&](s16x8 (*af)[4], const unsigned short* sb) {
    const char* B8 = (const char*)sb;
#pragma unroll
    for (int ks = 0; ks < 2; ++ks) {
      s16x8 bfr[4];
#pragma unroll
      for (int cf = 0; cf < 4; ++cf) {
        int row = wc * 64 + cf * 16 + l15;
        bfr[cf] = *(const s16x8*)(B8 + ((row * 128 + ks * 64 + l4 * 16) ^ ((row & 7) << 4)));
      }
#pragma unroll
      for (int rf = 0; rf < 4; ++rf)
#pragma unroll
        for (int cf = 0; cf < 4; ++cf)
          acc[rf][cf] = __builtin_amdgcn_mfma_f32_16x16x32_bf16(af[ks][rf], bfr[cf], acc[rf][cf], 0, 0, 0);
    }
  };

  unsigned short *p0 = Bs[0], *p1 = Bs[1], *p2 = Bs[2];

  stageB(0, p0);
  stageB(64, p1);
  loadA(0, afA);
  VMCNT(0);
  __builtin_amdgcn_s_barrier();
  CFENCE();

  for (int kp = 0; kp < 14; kp += 2) {         // 16 K-steps per K-half
    loadA((kp + 1) * 64, afB);
    stageB((kp + 2) * 64, p2);
    compute(afA, p0);
    VMCNT(2);
    __builtin_amdgcn_s_barrier();
    CFENCE();
    loadA((kp + 2) * 64, afA);
    stageB((kp + 3) * 64, p0);
    compute(afB, p1);
    VMCNT(2);
    __builtin_amdgcn_s_barrier();
    CFENCE();
    unsigned short* t = p0; p0 = p2; p2 = p1; p1 = t;
  }
  loadA(15 * 64, afB);
  compute(afA, p0);
  VMCNT(0);
  __builtin_amdgcn_s_barrier();
  CFENCE();
  compute(afB, p1);

  unsigned short* dz = down + (size_t)blockIdx.z * PP * DD;
#pragma unroll
  for (int rf = 0; rf < 4; ++rf) {
#pragma unroll
    for (int i = 0; i < 4; ++i) {
      int r = wr * 64 + rf * 16 + l4 * 4 + i;
      if (r < nrows) {
        int q = q0 + r;
        unsigned short* orow = dz + (size_t)q * DD + c0 + wc * 64 + l15;
#pragma unroll
        for (int cf = 0; cf < 4; ++cf) orow[cf * 16] = f2bf(acc[rf][cf][i]);
      }
    }
  }
}

// ---------------- combine: y[t] = sum over {pair a,b} x {K-half 0,1} of bf16 partials -----
__global__ void k_combine(const unsigned short* __restrict__ down, const int* __restrict__ pos,
                          float* __restrict__ y) {
  int i = blockIdx.x * blockDim.x + threadIdx.x;  // over TT*DD/8
  if (i >= TT * DD / 8) return;
  int t = i >> 7;            // DD/8 = 128 chunks per row
  int c8 = (i & 127) * 8;
  int qa = pos[2 * t], qb = pos[2 * t + 1];
  const unsigned short* d0 = down;
  const unsigned short* d1 = down + (size_t)PP * DD;
  s16x8 va0 = *reinterpret_cast<const s16x8*>(d0 + (size_t)qa * DD + c8);
  s16x8 va1 = *reinterpret_cast<const s16x8*>(d1 + (size_t)qa * DD + c8);
  s16x8 vb0 = *reinterpret_cast<const s16x8*>(d0 + (size_t)qb * DD + c8);
  s16x8 vb1 = *reinterpret_cast<const s16x8*>(d1 + (size_t)qb * DD + c8);
  float o[8];
#pragma unroll
  for (int j = 0; j < 8; ++j)
    o[j] = bf2f((unsigned short)va0[j]) + bf2f((unsigned short)va1[j]) +
           bf2f((unsigned short)vb0[j]) + bf2f((unsigned short)vb1[j]);
  float4* yo = reinterpret_cast<float4*>(y + (size_t)t * DD + c8);
  yo[0] = (float4){o[0], o[1], o[2], o[3]};
  yo[1] = (float4){o[4], o[5], o[6], o[7]};
}

extern "C" void kernel_launch(void* const* d_in, const int* in_sizes, int n_in,
                              void* d_out, int out_size, void* d_ws, size_t ws_size,
                              hipStream_t stream) {
  const float* x  = (const float*)d_in[0];
  const float* ep = (const float*)d_in[1];
  const int*   ei = (const int*)d_in[2];
  const float* W1 = (const float*)d_in[3];
  const float* W2 = (const float*)d_in[4];
  float* y = (float*)d_out;
  char* ws = (char*)d_ws;

  unsigned short* w1t = (unsigned short*)(ws + W1T_OFF);
  unsigned short* w2t = (unsigned short*)(ws + W2T_OFF);
  unsigned short* xb  = (unsigned short*)(ws + XB_OFF);
  unsigned short* ab  = (unsigned short*)(ws + ABUF_OFF);
  unsigned short* down = (unsigned short*)(ws + DOWN_OFF);
  int* meta   = (int*)(ws + META_OFF);
  int* plist  = (int*)(ws + PAIR_OFF);
  int* pos    = (int*)(ws + POS_OFF);

  hipLaunchKernelGGL(k_cvt_x, dim3(TT * DD / 4 / 256), dim3(256), 0, stream,
                     x, xb, TT * DD / 4);
  hipLaunchKernelGGL(k_transpose, dim3(CC1 / 64, DD / 64, EE), dim3(256), 0, stream,
                     W1, w1t, DD, CC1);
  hipLaunchKernelGGL(k_transpose, dim3(DD / 64, HH / 64, EE), dim3(256), 0, stream,
                     W2, w2t, HH, DD);
  hipLaunchKernelGGL(k_route, dim3(1), dim3(256), 0, stream, ei, meta, plist, pos);
  hipLaunchKernelGGL(k_gemm1, dim3(40, 32), dim3(512), 0, stream,
                     xb, w1t, ep, meta, plist, ab);
  hipLaunchKernelGGL(k_gemm2, dim3(40, 8, 2), dim3(512), 0, stream,
                     ab, w2t, meta, down);
  hipLaunchKernelGGL(k_combine, dim3(TT * DD / 8 / 256), dim3(256), 0, stream,
                     down, pos, y);
}

// Round 9
// 275.885 us; speedup vs baseline: 6.9703x; 6.9703x over previous
//
#include <hip/hip_runtime.h>
#include <hip/hip_bf16.h>
#include <math.h>

// Problem constants (fixed by the reference)
#define TT 4096   // tokens = B*S
#define PP 8192   // pairs  = TT*K
#define DD 1024   // model dim
#define HH 2048   // expert hidden
#define EE 8      // experts
#define CC1 4096  // 2H (up-proj width)

typedef __attribute__((ext_vector_type(8))) short s16x8;
typedef __attribute__((ext_vector_type(4))) float f32x4;

// ---------------- workspace layout (bytes) ----------------
#define W1T_OFF   0ull                                   // bf16 [E][4096][1024]  64 MB
#define W2T_OFF   (W1T_OFF + (size_t)EE*DD*CC1*2)        // bf16 [E][1024][2048]  32 MB
#define XB_OFF    (W2T_OFF + (size_t)EE*HH*DD*2)         // bf16 [T][1024]         8 MB
#define ABUF_OFF  (XB_OFF  + (size_t)TT*DD*2)            // bf16 [P][2048]        32 MB
#define DOWN_OFF  (ABUF_OFF + (size_t)PP*HH*2)           // bf16 [2][P][1024]     32 MB
#define META_OFF  (DOWN_OFF + (size_t)2*PP*DD*2)         // int meta[512] (2 KB)
#define PAIR_OFF  (META_OFF + 2048)                      // int [P]
#define POS_OFF   (PAIR_OFF + (size_t)PP*4)              // int [P]

#define VMCNT(N) asm volatile("s_waitcnt vmcnt(" #N ")" ::: "memory")
#define CFENCE() asm volatile("" ::: "memory")

__device__ __forceinline__ unsigned short f2bf(float f) {
  union { float f; unsigned u; } a; a.f = f;
  unsigned u = a.u;
  unsigned r = u + 0x7FFFu + ((u >> 16) & 1u);   // round-to-nearest-even
  return (unsigned short)(r >> 16);
}

__device__ __forceinline__ float bf2f(unsigned short s) {
  union { unsigned u; float f; } a; a.u = ((unsigned)s) << 16;
  return a.f;
}

// async global->LDS, 16B per lane; LDS dest must be wave-uniform base + lane*16
__device__ __forceinline__ void gload16(const void* g, void* l) {
  __builtin_amdgcn_global_load_lds(
      (const __attribute__((address_space(1))) void*)(uintptr_t)g,
      (__attribute__((address_space(3))) void*)(unsigned)(uintptr_t)l,
      16, 0, 0);
}

// ---------------- x -> bf16 ----------------
__global__ void k_cvt_x(const float* __restrict__ in, unsigned short* __restrict__ out, int n4) {
  int i = blockIdx.x * blockDim.x + threadIdx.x;
  if (i >= n4) return;
  float4 v = reinterpret_cast<const float4*>(in)[i];
  ushort4 o;
  o.x = f2bf(v.x); o.y = f2bf(v.y); o.z = f2bf(v.z); o.w = f2bf(v.w);
  reinterpret_cast<ushort4*>(out)[i] = o;
}

// ---------------- W [R][C] f32 -> Wt [C][R] bf16 (per matrix in grid.z) ----------------
__global__ __launch_bounds__(256) void k_transpose(const float* __restrict__ in,
                                                   unsigned short* __restrict__ out,
                                                   int R, int C) {
  __shared__ float t[64][65];
  const size_t mbase = (size_t)blockIdx.z * (size_t)R * (size_t)C;
  int c0 = blockIdx.x * 64, r0 = blockIdx.y * 64;
  int tid = threadIdx.x;
#pragma unroll
  for (int i = 0; i < 4; ++i) {
    int ch = tid + i * 256;            // 1024 chunks of float4
    int row = ch >> 4, c4 = (ch & 15) * 4;
    float4 v = *reinterpret_cast<const float4*>(&in[mbase + (size_t)(r0 + row) * C + c0 + c4]);
    t[row][c4] = v.x; t[row][c4 + 1] = v.y; t[row][c4 + 2] = v.z; t[row][c4 + 3] = v.w;
  }
  __syncthreads();
#pragma unroll
  for (int i = 0; i < 4; ++i) {
    int ch = tid + i * 256;
    int c = ch >> 4, rb = (ch & 15) * 4;
    ushort4 o;
    o.x = f2bf(t[rb][c]); o.y = f2bf(t[rb + 1][c]);
    o.z = f2bf(t[rb + 2][c]); o.w = f2bf(t[rb + 3][c]);
    *reinterpret_cast<ushort4*>(&out[mbase + (size_t)(c0 + c) * R + r0 + rb]) = o;
  }
}

// ---------------- routing: bucket pairs by expert, 256-row tile list, inverse perm ----------
// meta[0]=ntiles256; meta[1..9]=offsets[0..8]; meta[16+2i]/(17+2i) = (expert,q0)
__global__ void k_route(const int* __restrict__ eidx, int* __restrict__ meta,
                        int* __restrict__ plist, int* __restrict__ pos) {
  __shared__ int cnt[EE], off[EE + 1], cur[EE];
  int tid = threadIdx.x;
  if (tid < EE) { cnt[tid] = 0; cur[tid] = 0; }
  __syncthreads();
  for (int p = tid; p < PP; p += blockDim.x) atomicAdd(&cnt[eidx[p]], 1);
  __syncthreads();
  if (tid == 0) {
    int s = 0;
    for (int e = 0; e < EE; ++e) { off[e] = s; s += cnt[e]; }
    off[EE] = s;
    int n256 = 0;
    for (int e = 0; e < EE; ++e)
      for (int r = 0; r < cnt[e]; r += 256) {
        meta[16 + 2*n256] = e; meta[17 + 2*n256] = off[e] + r; ++n256;
      }
    meta[0] = n256;
    for (int e = 0; e <= EE; ++e) meta[1 + e] = off[e];
  }
  __syncthreads();
  for (int p = tid; p < PP; p += blockDim.x) {
    int e = eidx[p];
    int q = off[e] + atomicAdd(&cur[e], 1);
    plist[q] = p;
    pos[p] = q;
  }
}

// ---------------- GEMM1: up = x @ W1[e], fused GLU + gate, bf16 out (sorted order) ----------
// 256x128 tile (64 h-cols + paired 64 g-cols), BK=64, 8 waves (4Mx2N),
// depth-2 prefetch (3 LDS buffers), counted vmcnt(6) + raw s_barrier,
// T2 XOR-swizzle (both-sides), T1 bijective XCD swizzle: each XCD gets 4 contiguous
// W1 col-panels (1 MB, L2-resident) x all row-tiles.
// grid: 1280 blocks (flattened 40 row-tiles x 32 col-tiles); block 512
__global__ __launch_bounds__(512) void k_gemm1(
    const unsigned short* __restrict__ xb,     // [T][1024] bf16
    const unsigned short* __restrict__ w1t,    // [E][4096][1024] bf16 ([col][k])
    const float* __restrict__ gates,           // [P] f32
    const int* __restrict__ meta,
    const int* __restrict__ plist,
    unsigned short* __restrict__ abuf)         // [P][2048] bf16
{
  // T1: bijective XCD remap of the flat block id (1280 = 8 XCD x 160)
  const int bid = blockIdx.x;
  const int nb  = (bid & 7) * 160 + (bid >> 3);
  const int tb  = nb % 40;                     // row-tile (fast within XCD)
  const int cy  = nb / 40;                     // col-tile (4 per XCD)

  const int nt = meta[0];
  if (tb >= nt) return;
  const int e  = meta[16 + 2*tb];
  const int q0 = meta[17 + 2*tb];
  const int nrows = min(256, meta[2 + e] - q0);
  const int c0 = cy * 64;                      // h-col base

  __shared__ unsigned short As[3][256 * 64];   // 96 KB
  __shared__ unsigned short Bs[3][128 * 64];   // 48 KB

  const int tid = threadIdx.x;                 // 0..511
  const int wave = tid >> 6, lane = tid & 63;
  const int l15 = lane & 15, l4 = lane >> 4;
  const int wr = wave >> 1, wc = wave & 1;     // 4M x 2N wave grid

  const unsigned short* w1e = w1t + (size_t)e * CC1 * DD;

  const unsigned short* aga[4];
  const unsigned short* bga[2];
#pragma unroll
  for (int i = 0; i < 4; ++i) {
    int c = tid + i * 512;                     // 0..2047
    int row = c >> 3;                          // 0..255
    int ko = ((c & 7) ^ (row & 7)) * 8;
    int r = row < nrows ? row : 0;
    int p = plist[q0 + r];
    aga[i] = xb + (size_t)(p >> 1) * DD + ko;
  }
#pragma unroll
  for (int i = 0; i < 2; ++i) {
    int c = tid + i * 512;                     // 0..1023
    int row = c >> 3;                          // 0..127
    int ko = ((c & 7) ^ (row & 7)) * 8;
    int u = row & 63, wcq = row >> 6;
    int col = (u < 32) ? (c0 + wcq * 32 + u) : (HH + c0 + wcq * 32 + (u - 32));
    bga[i] = w1e + (size_t)col * DD + ko;
  }

  f32x4 acc[4][4];
#pragma unroll
  for (int a = 0; a < 4; ++a)
#pragma unroll
    for (int b = 0; b < 4; ++b) acc[a][b] = (f32x4)0.0f;

  auto stage = [&](int kk, unsigned short* pa, unsigned short* pb) {
#pragma unroll
    for (int i = 0; i < 4; ++i) gload16(aga[i] + kk, pa + (tid + i * 512) * 8);
#pragma unroll
    for (int i = 0; i < 2; ++i) gload16(bga[i] + kk, pb + (tid + i * 512) * 8);
  };

  auto compute_tile = [&](const unsigned short* sa, const unsigned short* sb) {
    const char* A8 = (const char*)sa;
    const char* B8 = (const char*)sb;
#pragma unroll
    for (int ks = 0; ks < 2; ++ks) {
      s16x8 af[4], bfr[4];
#pragma unroll
      for (int rf = 0; rf < 4; ++rf) {
        int row = wr * 64 + rf * 16 + l15;
        af[rf] = *(const s16x8*)(A8 + ((row * 128 + ks * 64 + l4 * 16) ^ ((row & 7) << 4)));
      }
#pragma unroll
      for (int cf = 0; cf < 4; ++cf) {
        int row = wc * 64 + cf * 16 + l15;
        bfr[cf] = *(const s16x8*)(B8 + ((row * 128 + ks * 64 + l4 * 16) ^ ((row & 7) << 4)));
      }
#pragma unroll
      for (int rf = 0; rf < 4; ++rf)
#pragma unroll
        for (int cf = 0; cf < 4; ++cf)
          acc[rf][cf] = __builtin_amdgcn_mfma_f32_16x16x32_bf16(af[rf], bfr[cf], acc[rf][cf], 0, 0, 0);
    }
  };

  unsigned short *a0 = As[0], *a1 = As[1], *a2 = As[2];
  unsigned short *b0 = Bs[0], *b1 = Bs[1], *b2 = Bs[2];

  stage(0, a0, b0);
  stage(64, a1, b1);
  VMCNT(6);                                    // tile 0 landed; tile 1 may fly
  __builtin_amdgcn_s_barrier();
  CFENCE();

  for (int kt = 0; kt < DD / 64 - 2; ++kt) {
    stage((kt + 2) * 64, a2, b2);              // prefetch depth 2
    compute_tile(a0, b0);
    VMCNT(6);                                  // all but newest K-tile landed
    __builtin_amdgcn_s_barrier();
    CFENCE();
    unsigned short* t;
    t = a0; a0 = a1; a1 = a2; a2 = t;
    t = b0; b0 = b1; b1 = b2; b2 = t;
  }
  compute_tile(a0, b0);                        // tile NT-2
  VMCNT(0);
  __builtin_amdgcn_s_barrier();
  CFENCE();
  compute_tile(a1, b1);                        // tile NT-1

  // Epilogue: a = gelu_exact(h) * (g+1) * gate, bf16.
#pragma unroll
  for (int rf = 0; rf < 4; ++rf) {
#pragma unroll
    for (int i = 0; i < 4; ++i) {
      int r = wr * 64 + rf * 16 + l4 * 4 + i;
      if (r < nrows) {
        int q = q0 + r;
        float gt = gates[plist[q]];
        unsigned short* orow = abuf + (size_t)q * HH + c0 + wc * 32 + l15;
#pragma unroll
        for (int cf = 0; cf < 2; ++cf) {
          float hv = acc[rf][cf][i];
          float gv = acc[rf][cf + 2][i];
          float av = 0.5f * hv * (1.0f + erff(hv * 0.70710678118654752f)) * (gv + 1.0f) * gt;
          orow[cf * 16] = f2bf(av);
        }
      }
    }
  }
}

// ---------------- GEMM2: down_z = a @ W2[e][kz:kz+1024], bf16 partials (K-split 2) --------
// Same 256x128 depth-2 counted-vmcnt swizzled structure + T1 XCD swizzle.
// grid: 640 blocks (flattened 40 x 8 x 2); block 512
__global__ __launch_bounds__(512) void k_gemm2(
    const unsigned short* __restrict__ abuf,   // [P][2048] bf16
    const unsigned short* __restrict__ w2t,    // [E][1024][2048] bf16 ([col][k])
    const int* __restrict__ meta,
    unsigned short* __restrict__ down)         // [2][P][1024] bf16
{
  // T1: bijective XCD remap (640 = 8 XCD x 80); each XCD gets 2 (cy,z) W2 panels
  const int bid = blockIdx.x;
  const int nb  = (bid & 7) * 80 + (bid >> 3);
  const int tb  = nb % 40;
  const int rr  = nb / 40;                     // 0..15
  const int cyy = rr & 7;
  const int zz  = rr >> 3;

  const int nt = meta[0];
  if (tb >= nt) return;
  const int e  = meta[16 + 2*tb];
  const int q0 = meta[17 + 2*tb];
  const int nrows = min(256, meta[2 + e] - q0);
  const int c0 = cyy * 128;
  const int kz = zz * (HH / 2);                // K-half base

  __shared__ unsigned short As[3][256 * 64];   // 96 KB
  __shared__ unsigned short Bs[3][128 * 64];   // 48 KB

  const int tid = threadIdx.x;
  const int wave = tid >> 6, lane = tid & 63;
  const int l15 = lane & 15, l4 = lane >> 4;
  const int wr = wave >> 1, wc = wave & 1;

  const unsigned short* w2e = w2t + (size_t)e * DD * HH;

  const unsigned short* aga[4];
  const unsigned short* bga[2];
#pragma unroll
  for (int i = 0; i < 4; ++i) {
    int c = tid + i * 512;
    int row = c >> 3;                          // 0..255
    int ko = ((c & 7) ^ (row & 7)) * 8;
    int r = row < nrows ? row : 0;
    aga[i] = abuf + (size_t)(q0 + r) * HH + kz + ko;
  }
#pragma unroll
  for (int i = 0; i < 2; ++i) {
    int c = tid + i * 512;
    int row = c >> 3;                          // 0..127
    int ko = ((c & 7) ^ (row & 7)) * 8;
    bga[i] = w2e + (size_t)(c0 + row) * HH + kz + ko;
  }

  f32x4 acc[4][4];
#pragma unroll
  for (int a = 0; a < 4; ++a)
#pragma unroll
    for (int b = 0; b < 4; ++b) acc[a][b] = (f32x4)0.0f;

  auto stage = [&](int kk, unsigned short* pa, unsigned short* pb) {
#pragma unroll
    for (int i = 0; i < 4; ++i) gload16(aga[i] + kk, pa + (tid + i * 512) * 8);
#pragma unroll
    for (int i = 0; i < 2; ++i) gload16(bga[i] + kk, pb + (tid + i * 512) * 8);
  };

  auto compute_tile = [&](const unsigned short* sa, const unsigned short* sb) {
    const char* A8 = (const char*)sa;
    const char* B8 = (const char*)sb;
#pragma unroll
    for (int ks = 0; ks < 2; ++ks) {
      s16x8 af[4], bfr[4];
#pragma unroll
      for (int rf = 0; rf < 4; ++rf) {
        int row = wr * 64 + rf * 16 + l15;
        af[rf] = *(const s16x8*)(A8 + ((row * 128 + ks * 64 + l4 * 16) ^ ((row & 7) << 4)));
      }
#pragma unroll
      for (int cf = 0; cf < 4; ++cf) {
        int row = wc * 64 + cf * 16 + l15;
        bfr[cf] = *(const s16x8*)(B8 + ((row * 128 + ks * 64 + l4 * 16) ^ ((row & 7) << 4)));
      }
#pragma unroll
      for (int rf = 0; rf < 4; ++rf)
#pragma unroll
        for (int cf = 0; cf < 4; ++cf)
          acc[rf][cf] = __builtin_amdgcn_mfma_f32_16x16x32_bf16(af[rf], bfr[cf], acc[rf][cf], 0, 0, 0);
    }
  };

  unsigned short *a0 = As[0], *a1 = As[1], *a2 = As[2];
  unsigned short *b0 = Bs[0], *b1 = Bs[1], *b2 = Bs[2];

  stage(0, a0, b0);
  stage(64, a1, b1);
  VMCNT(6);
  __builtin_amdgcn_s_barrier();
  CFENCE();

  const int NT = (HH / 2) / 64;                // 16 K-tiles per half
  for (int kt = 0; kt < NT - 2; ++kt) {
    stage((kt + 2) * 64, a2, b2);
    compute_tile(a0, b0);
    VMCNT(6);
    __builtin_amdgcn_s_barrier();
    CFENCE();
    unsigned short* t;
    t = a0; a0 = a1; a1 = a2; a2 = t;
    t = b0; b0 = b1; b1 = b2; b2 = t;
  }
  compute_tile(a0, b0);
  VMCNT(0);
  __builtin_amdgcn_s_barrier();
  CFENCE();
  compute_tile(a1, b1);

  unsigned short* dz = down + (size_t)zz * PP * DD;
#pragma unroll
  for (int rf = 0; rf < 4; ++rf) {
#pragma unroll
    for (int i = 0; i < 4; ++i) {
      int r = wr * 64 + rf * 16 + l4 * 4 + i;
      if (r < nrows) {
        int q = q0 + r;
        unsigned short* orow = dz + (size_t)q * DD + c0 + wc * 64 + l15;
#pragma unroll
        for (int cf = 0; cf < 4; ++cf) orow[cf * 16] = f2bf(acc[rf][cf][i]);
      }
    }
  }
}

// ---------------- combine: y[t] = sum over {pair a,b} x {K-half 0,1} of bf16 partials -----
__global__ void k_combine(const unsigned short* __restrict__ down, const int* __restrict__ pos,
                          float* __restrict__ y) {
  int i = blockIdx.x * blockDim.x + threadIdx.x;  // over TT*DD/8
  if (i >= TT * DD / 8) return;
  int t = i >> 7;            // DD/8 = 128 chunks per row
  int c8 = (i & 127) * 8;
  int qa = pos[2 * t], qb = pos[2 * t + 1];
  const unsigned short* d0 = down;
  const unsigned short* d1 = down + (size_t)PP * DD;
  s16x8 va0 = *reinterpret_cast<const s16x8*>(d0 + (size_t)qa * DD + c8);
  s16x8 va1 = *reinterpret_cast<const s16x8*>(d1 + (size_t)qa * DD + c8);
  s16x8 vb0 = *reinterpret_cast<const s16x8*>(d0 + (size_t)qb * DD + c8);
  s16x8 vb1 = *reinterpret_cast<const s16x8*>(d1 + (size_t)qb * DD + c8);
  float o[8];
#pragma unroll
  for (int j = 0; j < 8; ++j)
    o[j] = bf2f((unsigned short)va0[j]) + bf2f((unsigned short)va1[j]) +
           bf2f((unsigned short)vb0[j]) + bf2f((unsigned short)vb1[j]);
  float4* yo = reinterpret_cast<float4*>(y + (size_t)t * DD + c8);
  yo[0] = (float4){o[0], o[1], o[2], o[3]};
  yo[1] = (float4){o[4], o[5], o[6], o[7]};
}

extern "C" void kernel_launch(void* const* d_in, const int* in_sizes, int n_in,
                              void* d_out, int out_size, void* d_ws, size_t ws_size,
                              hipStream_t stream) {
  const float* x  = (const float*)d_in[0];
  const float* ep = (const float*)d_in[1];
  const int*   ei = (const int*)d_in[2];
  const float* W1 = (const float*)d_in[3];
  const float* W2 = (const float*)d_in[4];
  float* y = (float*)d_out;
  char* ws = (char*)d_ws;

  unsigned short* w1t = (unsigned short*)(ws + W1T_OFF);
  unsigned short* w2t = (unsigned short*)(ws + W2T_OFF);
  unsigned short* xb  = (unsigned short*)(ws + XB_OFF);
  unsigned short* ab  = (unsigned short*)(ws + ABUF_OFF);
  unsigned short* down = (unsigned short*)(ws + DOWN_OFF);
  int* meta   = (int*)(ws + META_OFF);
  int* plist  = (int*)(ws + PAIR_OFF);
  int* pos    = (int*)(ws + POS_OFF);

  hipLaunchKernelGGL(k_cvt_x, dim3(TT * DD / 4 / 256), dim3(256), 0, stream,
                     x, xb, TT * DD / 4);
  hipLaunchKernelGGL(k_transpose, dim3(CC1 / 64, DD / 64, EE), dim3(256), 0, stream,
                     W1, w1t, DD, CC1);
  hipLaunchKernelGGL(k_transpose, dim3(DD / 64, HH / 64, EE), dim3(256), 0, stream,
                     W2, w2t, HH, DD);
  hipLaunchKernelGGL(k_route, dim3(1), dim3(256), 0, stream, ei, meta, plist, pos);
  hipLaunchKernelGGL(k_gemm1, dim3(1280), dim3(512), 0, stream,
                     xb, w1t, ep, meta, plist, ab);
  hipLaunchKernelGGL(k_gemm2, dim3(640), dim3(512), 0, stream,
                     ab, w2t, meta, down);
  hipLaunchKernelGGL(k_combine, dim3(TT * DD / 8 / 256), dim3(256), 0, stream,
                     down, pos, y);
}

// Round 10
// 274.994 us; speedup vs baseline: 6.9929x; 1.0032x over previous
//
#include <hip/hip_runtime.h>
#include <hip/hip_bf16.h>
#include <math.h>

// Problem constants (fixed by the reference)
#define TT 4096   // tokens = B*S
#define PP 8192   // pairs  = TT*K
#define DD 1024   // model dim
#define HH 2048   // expert hidden
#define EE 8      // experts
#define CC1 4096  // 2H (up-proj width)

typedef __attribute__((ext_vector_type(8))) short s16x8;
typedef __attribute__((ext_vector_type(4))) float f32x4;

// ---------------- workspace layout (bytes) ----------------
#define W1T_OFF   0ull                                   // bf16 [E][4096][1024]  64 MB
#define W2T_OFF   (W1T_OFF + (size_t)EE*DD*CC1*2)        // bf16 [E][1024][2048]  32 MB
#define XB_OFF    (W2T_OFF + (size_t)EE*HH*DD*2)         // bf16 [T][1024]         8 MB
#define ABUF_OFF  (XB_OFF  + (size_t)TT*DD*2)            // bf16 [P][2048]        32 MB
#define DOWN_OFF  (ABUF_OFF + (size_t)PP*HH*2)           // bf16 [2][P][1024]     32 MB
#define META_OFF  (DOWN_OFF + (size_t)2*PP*DD*2)         // int meta[512] (2 KB)
#define PAIR_OFF  (META_OFF + 2048)                      // int [P]
#define POS_OFF   (PAIR_OFF + (size_t)PP*4)              // int [P]

#define VMCNT(N) asm volatile("s_waitcnt vmcnt(" #N ")" ::: "memory")
#define CFENCE() asm volatile("" ::: "memory")
// rule 18: pin MFMA after the wait (hipcc hoists reg-only MFMA past inline-asm lgkmcnt)
#define LGKM0() do { asm volatile("s_waitcnt lgkmcnt(0)" ::: "memory"); \
                     __builtin_amdgcn_sched_barrier(0); } while (0)

__device__ __forceinline__ unsigned short f2bf(float f) {
  union { float f; unsigned u; } a; a.f = f;
  unsigned u = a.u;
  unsigned r = u + 0x7FFFu + ((u >> 16) & 1u);   // round-to-nearest-even
  return (unsigned short)(r >> 16);
}

__device__ __forceinline__ float bf2f(unsigned short s) {
  union { unsigned u; float f; } a; a.u = ((unsigned)s) << 16;
  return a.f;
}

// async global->LDS, 16B per lane; LDS dest must be wave-uniform base + lane*16
__device__ __forceinline__ void gload16(const void* g, void* l) {
  __builtin_amdgcn_global_load_lds(
      (const __attribute__((address_space(1))) void*)(uintptr_t)g,
      (__attribute__((address_space(3))) void*)(unsigned)(uintptr_t)l,
      16, 0, 0);
}

// ---------------- x -> bf16 ----------------
__global__ void k_cvt_x(const float* __restrict__ in, unsigned short* __restrict__ out, int n4) {
  int i = blockIdx.x * blockDim.x + threadIdx.x;
  if (i >= n4) return;
  float4 v = reinterpret_cast<const float4*>(in)[i];
  ushort4 o;
  o.x = f2bf(v.x); o.y = f2bf(v.y); o.z = f2bf(v.z); o.w = f2bf(v.w);
  reinterpret_cast<ushort4*>(out)[i] = o;
}

// ---------------- W [R][C] f32 -> Wt [C][R] bf16 (per matrix in grid.z) ----------------
__global__ __launch_bounds__(256) void k_transpose(const float* __restrict__ in,
                                                   unsigned short* __restrict__ out,
                                                   int R, int C) {
  __shared__ float t[64][65];
  const size_t mbase = (size_t)blockIdx.z * (size_t)R * (size_t)C;
  int c0 = blockIdx.x * 64, r0 = blockIdx.y * 64;
  int tid = threadIdx.x;
#pragma unroll
  for (int i = 0; i < 4; ++i) {
    int ch = tid + i * 256;            // 1024 chunks of float4
    int row = ch >> 4, c4 = (ch & 15) * 4;
    float4 v = *reinterpret_cast<const float4*>(&in[mbase + (size_t)(r0 + row) * C + c0 + c4]);
    t[row][c4] = v.x; t[row][c4 + 1] = v.y; t[row][c4 + 2] = v.z; t[row][c4 + 3] = v.w;
  }
  __syncthreads();
#pragma unroll
  for (int i = 0; i < 4; ++i) {
    int ch = tid + i * 256;
    int c = ch >> 4, rb = (ch & 15) * 4;
    ushort4 o;
    o.x = f2bf(t[rb][c]); o.y = f2bf(t[rb + 1][c]);
    o.z = f2bf(t[rb + 2][c]); o.w = f2bf(t[rb + 3][c]);
    *reinterpret_cast<ushort4*>(&out[mbase + (size_t)(c0 + c) * R + r0 + rb]) = o;
  }
}

// ---------------- routing: bucket pairs by expert, 256-row tile list, inverse perm ----------
// meta[0]=ntiles256; meta[1..9]=offsets[0..8]; meta[16+2i]/(17+2i) = (expert,q0)
__global__ void k_route(const int* __restrict__ eidx, int* __restrict__ meta,
                        int* __restrict__ plist, int* __restrict__ pos) {
  __shared__ int cnt[EE], off[EE + 1], cur[EE];
  int tid = threadIdx.x;
  if (tid < EE) { cnt[tid] = 0; cur[tid] = 0; }
  __syncthreads();
  for (int p = tid; p < PP; p += blockDim.x) atomicAdd(&cnt[eidx[p]], 1);
  __syncthreads();
  if (tid == 0) {
    int s = 0;
    for (int e = 0; e < EE; ++e) { off[e] = s; s += cnt[e]; }
    off[EE] = s;
    int n256 = 0;
    for (int e = 0; e < EE; ++e)
      for (int r = 0; r < cnt[e]; r += 256) {
        meta[16 + 2*n256] = e; meta[17 + 2*n256] = off[e] + r; ++n256;
      }
    meta[0] = n256;
    for (int e = 0; e <= EE; ++e) meta[1 + e] = off[e];
  }
  __syncthreads();
  for (int p = tid; p < PP; p += blockDim.x) {
    int e = eidx[p];
    int q = off[e] + atomicAdd(&cur[e], 1);
    plist[q] = p;
    pos[p] = q;
  }
}

// ---------------- GEMM1: up = x @ W1[e], fused GLU + gate, bf16 out (sorted order) ----------
// 256x128 tile (64 h + paired 64 g cols), BK=64, 8 waves (4Mx2N), 3 LDS buffers depth-2.
// Phase-split schedule (T3): per K-tile 2 phases, each {8 ds_read_b128 + 3 gload ->
// s_barrier -> lgkmcnt(0) -> setprio(1) 16 MFMA setprio(0) -> s_barrier}; counted
// vmcnt(6) once per K-tile (T4); T2 both-sides XOR swizzle; T5 setprio.
// grid: (40 row-tiles, 32 col-tiles); block 512
__global__ __launch_bounds__(512) void k_gemm1(
    const unsigned short* __restrict__ xb,     // [T][1024] bf16
    const unsigned short* __restrict__ w1t,    // [E][4096][1024] bf16 ([col][k])
    const float* __restrict__ gates,           // [P] f32
    const int* __restrict__ meta,
    const int* __restrict__ plist,
    unsigned short* __restrict__ abuf)         // [P][2048] bf16
{
  const int nt = meta[0];
  const int tb = blockIdx.x;
  if (tb >= nt) return;
  const int e  = meta[16 + 2*tb];
  const int q0 = meta[17 + 2*tb];
  const int nrows = min(256, meta[2 + e] - q0);
  const int c0 = blockIdx.y * 64;              // h-col base

  __shared__ unsigned short As[3][256 * 64];   // 96 KB
  __shared__ unsigned short Bs[3][128 * 64];   // 48 KB

  const int tid = threadIdx.x;                 // 0..511
  const int wave = tid >> 6, lane = tid & 63;
  const int l15 = lane & 15, l4 = lane >> 4;
  const int wr = wave >> 1, wc = wave & 1;     // 4M x 2N wave grid

  const unsigned short* w1e = w1t + (size_t)e * CC1 * DD;

  const unsigned short* aga[4];
  const unsigned short* bga[2];
#pragma unroll
  for (int i = 0; i < 4; ++i) {
    int c = tid + i * 512;                     // 0..2047
    int row = c >> 3;                          // 0..255
    int ko = ((c & 7) ^ (row & 7)) * 8;
    int r = row < nrows ? row : 0;
    int p = plist[q0 + r];
    aga[i] = xb + (size_t)(p >> 1) * DD + ko;
  }
#pragma unroll
  for (int i = 0; i < 2; ++i) {
    int c = tid + i * 512;                     // 0..1023
    int row = c >> 3;                          // 0..127
    int ko = ((c & 7) ^ (row & 7)) * 8;
    int u = row & 63, wcq = row >> 6;
    int col = (u < 32) ? (c0 + wcq * 32 + u) : (HH + c0 + wcq * 32 + (u - 32));
    bga[i] = w1e + (size_t)col * DD + ko;
  }

  f32x4 acc[4][4];
#pragma unroll
  for (int a = 0; a < 4; ++a)
#pragma unroll
    for (int b = 0; b < 4; ++b) acc[a][b] = (f32x4)0.0f;

  auto stage_h0 = [&](int kk, unsigned short* pa, unsigned short* pb) {
    gload16(aga[0] + kk, pa + (tid + 0 * 512) * 8);
    gload16(aga[1] + kk, pa + (tid + 1 * 512) * 8);
    gload16(bga[0] + kk, pb + (tid + 0 * 512) * 8);
  };
  auto stage_h1 = [&](int kk, unsigned short* pa, unsigned short* pb) {
    gload16(aga[2] + kk, pa + (tid + 2 * 512) * 8);
    gload16(aga[3] + kk, pa + (tid + 3 * 512) * 8);
    gload16(bga[1] + kk, pb + (tid + 1 * 512) * 8);
  };

  auto dsread = [&](const unsigned short* sa, const unsigned short* sb, int ks,
                    s16x8* af, s16x8* bfr) {
    const char* A8 = (const char*)sa;
    const char* B8 = (const char*)sb;
#pragma unroll
    for (int rf = 0; rf < 4; ++rf) {
      int row = wr * 64 + rf * 16 + l15;
      af[rf] = *(const s16x8*)(A8 + ((row * 128 + ks * 64 + l4 * 16) ^ ((row & 7) << 4)));
    }
#pragma unroll
    for (int cf = 0; cf < 4; ++cf) {
      int row = wc * 64 + cf * 16 + l15;
      bfr[cf] = *(const s16x8*)(B8 + ((row * 128 + ks * 64 + l4 * 16) ^ ((row & 7) << 4)));
    }
  };
  auto mfma16 = [&](const s16x8* af, const s16x8* bfr) {
    __builtin_amdgcn_s_setprio(1);
#pragma unroll
    for (int rf = 0; rf < 4; ++rf)
#pragma unroll
      for (int cf = 0; cf < 4; ++cf)
        acc[rf][cf] = __builtin_amdgcn_mfma_f32_16x16x32_bf16(af[rf], bfr[cf], acc[rf][cf], 0, 0, 0);
    __builtin_amdgcn_s_setprio(0);
  };

  unsigned short *a0 = As[0], *a1 = As[1], *a2 = As[2];
  unsigned short *b0 = Bs[0], *b1 = Bs[1], *b2 = Bs[2];

  // prologue: tiles 0 and 1 staged
  stage_h0(0, a0, b0);  stage_h1(0, a0, b0);
  stage_h0(64, a1, b1); stage_h1(64, a1, b1);
  VMCNT(6);                                    // tile 0 landed; tile 1 may fly
  __builtin_amdgcn_s_barrier();
  CFENCE();

  s16x8 af[4], bfr[4];
  for (int kt = 0; kt < DD / 64 - 2; ++kt) {
    const int kk = (kt + 2) * 64;
    // phase 0 (ks=0)
    dsread(a0, b0, 0, af, bfr);
    stage_h0(kk, a2, b2);
    __builtin_amdgcn_s_barrier();
    LGKM0();
    mfma16(af, bfr);
    __builtin_amdgcn_s_barrier();
    // phase 1 (ks=1)
    dsread(a0, b0, 1, af, bfr);
    stage_h1(kk, a2, b2);
    VMCNT(6);                                  // tile kt+1 landed; kt+2's 6 loads fly
    __builtin_amdgcn_s_barrier();
    LGKM0();
    mfma16(af, bfr);
    __builtin_amdgcn_s_barrier();
    CFENCE();
    unsigned short* t;
    t = a0; a0 = a1; a1 = a2; a2 = t;
    t = b0; b0 = b1; b1 = b2; b2 = t;
  }
  // tile NT-2 (landed); tile NT-1 still flying
  dsread(a0, b0, 0, af, bfr);
  __builtin_amdgcn_s_barrier();
  LGKM0();
  mfma16(af, bfr);
  __builtin_amdgcn_s_barrier();
  dsread(a0, b0, 1, af, bfr);
  VMCNT(0);                                    // tile NT-1 landed
  __builtin_amdgcn_s_barrier();
  LGKM0();
  mfma16(af, bfr);
  __builtin_amdgcn_s_barrier();
  // tile NT-1 (no more LDS writes -> no barriers needed)
  dsread(a1, b1, 0, af, bfr);
  LGKM0();
  mfma16(af, bfr);
  dsread(a1, b1, 1, af, bfr);
  LGKM0();
  mfma16(af, bfr);

  // Epilogue: a = gelu_exact(h) * (g+1) * gate, bf16.
#pragma unroll
  for (int rf = 0; rf < 4; ++rf) {
#pragma unroll
    for (int i = 0; i < 4; ++i) {
      int r = wr * 64 + rf * 16 + l4 * 4 + i;
      if (r < nrows) {
        int q = q0 + r;
        float gt = gates[plist[q]];
        unsigned short* orow = abuf + (size_t)q * HH + c0 + wc * 32 + l15;
#pragma unroll
        for (int cf = 0; cf < 2; ++cf) {
          float hv = acc[rf][cf][i];
          float gv = acc[rf][cf + 2][i];
          float av = 0.5f * hv * (1.0f + erff(hv * 0.70710678118654752f)) * (gv + 1.0f) * gt;
          orow[cf * 16] = f2bf(av);
        }
      }
    }
  }
}

// ---------------- GEMM2: down_z = a @ W2[e][kz:kz+1024], bf16 partials (K-split 2) --------
// Same phase-split schedule; grid: (40 row-tiles, 8 col-tiles of 128, 2 K-halves); block 512
__global__ __launch_bounds__(512) void k_gemm2(
    const unsigned short* __restrict__ abuf,   // [P][2048] bf16
    const unsigned short* __restrict__ w2t,    // [E][1024][2048] bf16 ([col][k])
    const int* __restrict__ meta,
    unsigned short* __restrict__ down)         // [2][P][1024] bf16
{
  const int nt = meta[0];
  const int tb = blockIdx.x;
  if (tb >= nt) return;
  const int e  = meta[16 + 2*tb];
  const int q0 = meta[17 + 2*tb];
  const int nrows = min(256, meta[2 + e] - q0);
  const int c0 = blockIdx.y * 128;
  const int kz = blockIdx.z * (HH / 2);        // K-half base

  __shared__ unsigned short As[3][256 * 64];   // 96 KB
  __shared__ unsigned short Bs[3][128 * 64];   // 48 KB

  const int tid = threadIdx.x;
  const int wave = tid >> 6, lane = tid & 63;
  const int l15 = lane & 15, l4 = lane >> 4;
  const int wr = wave >> 1, wc = wave & 1;

  const unsigned short* w2e = w2t + (size_t)e * DD * HH;

  const unsigned short* aga[4];
  const unsigned short* bga[2];
#pragma unroll
  for (int i = 0; i < 4; ++i) {
    int c = tid + i * 512;
    int row = c >> 3;                          // 0..255
    int ko = ((c & 7) ^ (row & 7)) * 8;
    int r = row < nrows ? row : 0;
    aga[i] = abuf + (size_t)(q0 + r) * HH + kz + ko;
  }
#pragma unroll
  for (int i = 0; i < 2; ++i) {
    int c = tid + i * 512;
    int row = c >> 3;                          // 0..127
    int ko = ((c & 7) ^ (row & 7)) * 8;
    bga[i] = w2e + (size_t)(c0 + row) * HH + kz + ko;
  }

  f32x4 acc[4][4];
#pragma unroll
  for (int a = 0; a < 4; ++a)
#pragma unroll
    for (int b = 0; b < 4; ++b) acc[a][b] = (f32x4)0.0f;

  auto stage_h0 = [&](int kk, unsigned short* pa, unsigned short* pb) {
    gload16(aga[0] + kk, pa + (tid + 0 * 512) * 8);
    gload16(aga[1] + kk, pa + (tid + 1 * 512) * 8);
    gload16(bga[0] + kk, pb + (tid + 0 * 512) * 8);
  };
  auto stage_h1 = [&](int kk, unsigned short* pa, unsigned short* pb) {
    gload16(aga[2] + kk, pa + (tid + 2 * 512) * 8);
    gload16(aga[3] + kk, pa + (tid + 3 * 512) * 8);
    gload16(bga[1] + kk, pb + (tid + 1 * 512) * 8);
  };
  auto dsread = [&](const unsigned short* sa, const unsigned short* sb, int ks,
                    s16x8* af, s16x8* bfr) {
    const char* A8 = (const char*)sa;
    const char* B8 = (const char*)sb;
#pragma unroll
    for (int rf = 0; rf < 4; ++rf) {
      int row = wr * 64 + rf * 16 + l15;
      af[rf] = *(const s16x8*)(A8 + ((row * 128 + ks * 64 + l4 * 16) ^ ((row & 7) << 4)));
    }
#pragma unroll
    for (int cf = 0; cf < 4; ++cf) {
      int row = wc * 64 + cf * 16 + l15;
      bfr[cf] = *(const s16x8*)(B8 + ((row * 128 + ks * 64 + l4 * 16) ^ ((row & 7) << 4)));
    }
  };
  auto mfma16 = [&](const s16x8* af, const s16x8* bfr) {
    __builtin_amdgcn_s_setprio(1);
#pragma unroll
    for (int rf = 0; rf < 4; ++rf)
#pragma unroll
      for (int cf = 0; cf < 4; ++cf)
        acc[rf][cf] = __builtin_amdgcn_mfma_f32_16x16x32_bf16(af[rf], bfr[cf], acc[rf][cf], 0, 0, 0);
    __builtin_amdgcn_s_setprio(0);
  };

  unsigned short *a0 = As[0], *a1 = As[1], *a2 = As[2];
  unsigned short *b0 = Bs[0], *b1 = Bs[1], *b2 = Bs[2];

  stage_h0(0, a0, b0);  stage_h1(0, a0, b0);
  stage_h0(64, a1, b1); stage_h1(64, a1, b1);
  VMCNT(6);
  __builtin_amdgcn_s_barrier();
  CFENCE();

  s16x8 af[4], bfr[4];
  const int NT = (HH / 2) / 64;                // 16 K-tiles per half
  for (int kt = 0; kt < NT - 2; ++kt) {
    const int kk = (kt + 2) * 64;
    dsread(a0, b0, 0, af, bfr);
    stage_h0(kk, a2, b2);
    __builtin_amdgcn_s_barrier();
    LGKM0();
    mfma16(af, bfr);
    __builtin_amdgcn_s_barrier();
    dsread(a0, b0, 1, af, bfr);
    stage_h1(kk, a2, b2);
    VMCNT(6);
    __builtin_amdgcn_s_barrier();
    LGKM0();
    mfma16(af, bfr);
    __builtin_amdgcn_s_barrier();
    CFENCE();
    unsigned short* t;
    t = a0; a0 = a1; a1 = a2; a2 = t;
    t = b0; b0 = b1; b1 = b2; b2 = t;
  }
  dsread(a0, b0, 0, af, bfr);
  __builtin_amdgcn_s_barrier();
  LGKM0();
  mfma16(af, bfr);
  __builtin_amdgcn_s_barrier();
  dsread(a0, b0, 1, af, bfr);
  VMCNT(0);
  __builtin_amdgcn_s_barrier();
  LGKM0();
  mfma16(af, bfr);
  __builtin_amdgcn_s_barrier();
  dsread(a1, b1, 0, af, bfr);
  LGKM0();
  mfma16(af, bfr);
  dsread(a1, b1, 1, af, bfr);
  LGKM0();
  mfma16(af, bfr);

  unsigned short* dz = down + (size_t)blockIdx.z * PP * DD;
#pragma unroll
  for (int rf = 0; rf < 4; ++rf) {
#pragma unroll
    for (int i = 0; i < 4; ++i) {
      int r = wr * 64 + rf * 16 + l4 * 4 + i;
      if (r < nrows) {
        int q = q0 + r;
        unsigned short* orow = dz + (size_t)q * DD + c0 + wc * 64 + l15;
#pragma unroll
        for (int cf = 0; cf < 4; ++cf) orow[cf * 16] = f2bf(acc[rf][cf][i]);
      }
    }
  }
}

// ---------------- combine: y[t] = sum over {pair a,b} x {K-half 0,1} of bf16 partials -----
__global__ void k_combine(const unsigned short* __restrict__ down, const int* __restrict__ pos,
                          float* __restrict__ y) {
  int i = blockIdx.x * blockDim.x + threadIdx.x;  // over TT*DD/8
  if (i >= TT * DD / 8) return;
  int t = i >> 7;            // DD/8 = 128 chunks per row
  int c8 = (i & 127) * 8;
  int qa = pos[2 * t], qb = pos[2 * t + 1];
  const unsigned short* d0 = down;
  const unsigned short* d1 = down + (size_t)PP * DD;
  s16x8 va0 = *reinterpret_cast<const s16x8*>(d0 + (size_t)qa * DD + c8);
  s16x8 va1 = *reinterpret_cast<const s16x8*>(d1 + (size_t)qa * DD + c8);
  s16x8 vb0 = *reinterpret_cast<const s16x8*>(d0 + (size_t)qb * DD + c8);
  s16x8 vb1 = *reinterpret_cast<const s16x8*>(d1 + (size_t)qb * DD + c8);
  float o[8];
#pragma unroll
  for (int j = 0; j < 8; ++j)
    o[j] = bf2f((unsigned short)va0[j]) + bf2f((unsigned short)va1[j]) +
           bf2f((unsigned short)vb0[j]) + bf2f((unsigned short)vb1[j]);
  float4* yo = reinterpret_cast<float4*>(y + (size_t)t * DD + c8);
  yo[0] = (float4){o[0], o[1], o[2], o[3]};
  yo[1] = (float4){o[4], o[5], o[6], o[7]};
}

extern "C" void kernel_launch(void* const* d_in, const int* in_sizes, int n_in,
                              void* d_out, int out_size, void* d_ws, size_t ws_size,
                              hipStream_t stream) {
  const float* x  = (const float*)d_in[0];
  const float* ep = (const float*)d_in[1];
  const int*   ei = (const int*)d_in[2];
  const float* W1 = (const float*)d_in[3];
  const float* W2 = (const float*)d_in[4];
  float* y = (float*)d_out;
  char* ws = (char*)d_ws;

  unsigned short* w1t = (unsigned short*)(ws + W1T_OFF);
  unsigned short* w2t = (unsigned short*)(ws + W2T_OFF);
  unsigned short* xb  = (unsigned short*)(ws + XB_OFF);
  unsigned short* ab  = (unsigned short*)(ws + ABUF_OFF);
  unsigned short* down = (unsigned short*)(ws + DOWN_OFF);
  int* meta   = (int*)(ws + META_OFF);
  int* plist  = (int*)(ws + PAIR_OFF);
  int* pos    = (int*)(ws + POS_OFF);

  hipLaunchKernelGGL(k_cvt_x, dim3(TT * DD / 4 / 256), dim3(256), 0, stream,
                     x, xb, TT * DD / 4);
  hipLaunchKernelGGL(k_transpose, dim3(CC1 / 64, DD / 64, EE), dim3(256), 0, stream,
                     W1, w1t, DD, CC1);
  hipLaunchKernelGGL(k_transpose, dim3(DD / 64, HH / 64, EE), dim3(256), 0, stream,
                     W2, w2t, HH, DD);
  hipLaunchKernelGGL(k_route, dim3(1), dim3(256), 0, stream, ei, meta, plist, pos);
  hipLaunchKernelGGL(k_gemm1, dim3(40, 32), dim3(512), 0, stream,
                     xb, w1t, ep, meta, plist, ab);
  hipLaunchKernelGGL(k_gemm2, dim3(40, 8, 2), dim3(512), 0, stream,
                     ab, w2t, meta, down);
  hipLaunchKernelGGL(k_combine, dim3(TT * DD / 8 / 256), dim3(256), 0, stream,
                     down, pos, y);
}